// Round 3
// baseline (682.104 us; speedup 1.0000x reference)
//
#include <hip/hip_runtime.h>

#define BS 1024
#define TS 64

__device__ __forceinline__ float sigf(float x){ return 1.f/(1.f+__expf(-x)); }
__device__ __forceinline__ float tanh_fast(float x){
  float cx = fminf(fmaxf(x,-15.f),15.f);
  float e = __expf(2.f*cx);
  return (e-1.f)/(e+1.f);
}
__device__ __forceinline__ float lrelu(float v){ return v>=0.f ? v : 0.1f*v; }
__device__ __forceinline__ float dot4(float4 a, float4 b){
  return a.x*b.x + a.y*b.y + a.z*b.z + a.w*b.w;
}

// ---------------- Kernel A: batch-independent precompute ----------------
// ws_wcomb[64*64] = Wmix[:,64:] @ Wof
// ws_mbias[TS*64] : per-step mix bias (teom LSTM + Wtf + Wmix1 folded)
__global__ __launch_bounds__(256) void precompute_kernel(
    const float* __restrict__ Whh_t, const float* __restrict__ bih_t,
    const float* __restrict__ bhh_t,
    const float* __restrict__ Wof,  const float* __restrict__ bof,
    const float* __restrict__ Wtf,  const float* __restrict__ btf,
    const float* __restrict__ Wmix, const float* __restrict__ bmix,
    float* __restrict__ ws_wcomb, float* __restrict__ ws_mbias)
{
  __shared__ __align__(16) float sHall[TS*64];
  __shared__ __align__(16) float sTs[TS*64];
  __shared__ float sWof[64*64];
  __shared__ float sG[256];
  __shared__ float sBof[64];
  __shared__ float sCmr[64];

  const int t = threadIdx.x;

  float4 wrow[16];
#pragma unroll
  for (int j=0;j<16;++j) wrow[j] = reinterpret_cast<const float4*>(Whh_t + t*64)[j];
  const float btr = bih_t[t] + bhh_t[t];

  for (int i=t;i<4096;i+=256) sWof[i] = Wof[i];
  if (t<64) sBof[t] = bof[t];
  __syncthreads();

  float c_reg = 0.f;
  for (int s=0;s<TS;++s){
    float a0=btr, a1=0.f, a2=0.f, a3=0.f;
    if (s>0){
      const float4* h4 = reinterpret_cast<const float4*>(sHall + (s-1)*64);
#pragma unroll
      for (int j=0;j<16;j+=4){
        a0 += dot4(wrow[j],   h4[j]);
        a1 += dot4(wrow[j+1], h4[j+1]);
        a2 += dot4(wrow[j+2], h4[j+2]);
        a3 += dot4(wrow[j+3], h4[j+3]);
      }
    }
    sG[t] = (a0+a1)+(a2+a3);
    __syncthreads();
    if (t<64){
      float gi=sG[t], gf=sG[64+t], gg=sG[128+t], go=sG[192+t];
      c_reg = sigf(gf)*c_reg + sigf(gi)*tanh_fast(gg);
      sHall[s*64+t] = sigf(go)*tanh_fast(c_reg);
    }
    __syncthreads();
  }

  if (t<64){
    float acc = bmix[t];
    for (int k=0;k<64;++k) acc += Wmix[t*128+64+k]*sBof[k];
    sCmr[t] = acc;
  }
  for (int o=t;o<TS*64;o+=256){
    int s=o>>6, i=o&63;
    float acc = btf[i];
    for (int k=0;k<64;++k) acc += Wtf[i*64+k]*sHall[s*64+k];
    sTs[o] = acc;
  }
  for (int o=t;o<4096;o+=256){
    int r=o>>6, j=o&63;
    float acc = 0.f;
    for (int k=0;k<64;++k) acc += Wmix[r*128+64+k]*sWof[k*64+j];
    ws_wcomb[o] = acc;
  }
  __syncthreads();
  for (int o=t;o<TS*64;o+=256){
    int s=o>>6, j=o&63;
    float acc = sCmr[j];
    for (int k=0;k<64;++k) acc += Wmix[j*128+k]*sTs[s*64+k];
    ws_mbias[o] = acc;
  }
}

// ---------------- Kernel B: 4 batches/block, 256 thr, 1 wave = 1 batch tail ----------------
// Gate layout (R1-proven): thread t holds gate row t's weights ONCE in 64 VGPR
// and computes that row for all 4 batches (4x weight reuse, 8 accumulators,
// h via wave-uniform broadcast LDS reads). After B1, EVERY wave runs the full
// serial tail (cell->mix->MLP->head) for its own batch -> no idle waves.
__global__ __launch_bounds__(256, 1) void main_kernel(
    const float* __restrict__ obsv,
    const float* __restrict__ Wih_o, const float* __restrict__ Whh_o,
    const float* __restrict__ bih_o, const float* __restrict__ bhh_o,
    const float* __restrict__ W1, const float* __restrict__ b1,
    const float* __restrict__ W2, const float* __restrict__ b2,
    const float* __restrict__ W3, const float* __restrict__ b3,
    const float* __restrict__ wcomb, const float* __restrict__ mbias,
    float* __restrict__ out)
{
  __shared__ __align__(16) float4 sWc[16*64];  // [q][row] 16 KB
  __shared__ __align__(16) float4 sW1[16*32];  // [q][row] 8 KB
  __shared__ __align__(16) float4 sW2[8*32];   // [q][row] 4 KB
  __shared__ float sG[4*256];                  // 4 KB
  __shared__ __align__(16) float sHb[4*64];
  __shared__ __align__(16) float sM[4*64];
  __shared__ __align__(16) float sA1[4*32];
  __shared__ float sY[4*2];
  __shared__ float sObs[4*16];

  const int t    = threadIdx.x;
  const int blk  = blockIdx.x;
  const int lane = t & 63;
  const int w    = t >> 6;          // wave = batch within block

  out[BS*TS*2 + blk*256 + t] = 0.f;   // c_out zeros (256 blk * 256 = 65536)

  // staging (row->[q][row] transposed-packed)
  for (int i=t;i<1024;i+=256) sWc[i] = reinterpret_cast<const float4*>(wcomb)[(i&63)*16 + (i>>6)];
  for (int i=t;i<512;i+=256)  sW1[i] = reinterpret_cast<const float4*>(W1)[(i&31)*16 + (i>>5)];
  if (t<256)                  sW2[t] = reinterpret_cast<const float4*>(W2)[(t&31)*8 + (t>>5)];
  if (t<64) sObs[t] = obsv[blk*64 + t];
  sHb[t] = 0.f;                      // 4*64 = 256

  // gate row t weights (shared across the 4 batches -> 4x reuse)
  float4 wrow[16];
#pragma unroll
  for (int j=0;j<16;++j) wrow[j] = reinterpret_cast<const float4*>(Whh_o + t*64)[j];
  const float wi0  = Wih_o[2*t];
  const float wi1  = Wih_o[2*t+1];
  const float b_or = bih_o[t] + bhh_o[t];

  // tail constants (every wave is a tail wave)
  const int rr = lane & 31, hf = lane >> 5;
  const float b1r = b1[rr], b2r = b2[rr];
  const float w30 = W3[rr], w31 = W3[32+rr];
  const float b30 = b3[0],  b31 = b3[1];

  __syncthreads();   // staging + sHb zero visible

  float bl00 = sObs[w*16+10], bl01 = sObs[w*16+11];
  float bl10 = sObs[w*16+12], bl11 = sObs[w*16+13];
  float bl20 = sObs[w*16+14], bl21 = sObs[w*16+15];
  float c_reg = 0.f;

  const float4* sH4   = reinterpret_cast<const float4*>(sHb);
  const float4* sH4w  = reinterpret_cast<const float4*>(sHb + w*64);
  const float4* sM4w  = reinterpret_cast<const float4*>(sM  + w*64);
  const float4* sA14w = reinterpret_cast<const float4*>(sA1 + w*32);

  for (int it=0; it<71; ++it){
    // prefetch mbias (L2-resident) under gate FMAs
    float mb = 0.f;
    if (it >= 7) mb = mbias[(it-7)*64 + lane];

    // ---- gates: row t for 4 batches (identical even/odd 2-acc FP order) ----
    float a0,a1,a2,a3,p0,p1,p2,p3;
    {
      float x00,x01,x10,x11,x20,x21,x30,x31;
      if (it < 8){
        x00=sObs[   2*it]; x01=sObs[   2*it+1];
        x10=sObs[16+2*it]; x11=sObs[16+2*it+1];
        x20=sObs[32+2*it]; x21=sObs[32+2*it+1];
        x30=sObs[48+2*it]; x31=sObs[48+2*it+1];
      } else {
        x00=sY[0]; x01=sY[1]; x10=sY[2]; x11=sY[3];
        x20=sY[4]; x21=sY[5]; x30=sY[6]; x31=sY[7];
      }
      a0 = b_or + wi0*x00 + wi1*x01; p0 = 0.f;
      a1 = b_or + wi0*x10 + wi1*x11; p1 = 0.f;
      a2 = b_or + wi0*x20 + wi1*x21; p2 = 0.f;
      a3 = b_or + wi0*x30 + wi1*x31; p3 = 0.f;
    }
#pragma unroll
    for (int q=0;q<16;q+=2){
      const float4 wa = wrow[q], wb = wrow[q+1];
      a0 += dot4(wa, sH4[q]);       p0 += dot4(wb, sH4[q+1]);
      a1 += dot4(wa, sH4[16+q]);    p1 += dot4(wb, sH4[16+q+1]);
      a2 += dot4(wa, sH4[32+q]);    p2 += dot4(wb, sH4[32+q+1]);
      a3 += dot4(wa, sH4[48+q]);    p3 += dot4(wb, sH4[48+q+1]);
    }
    sG[      t] = a0 + p0;
    sG[256 + t] = a1 + p1;
    sG[512 + t] = a2 + p2;
    sG[768 + t] = a3 + p3;
    __syncthreads();   // B1: sG ready

    // ---- tail: wave w = batch w (all waves active) ----
    {
      const float g0 = sG[w*256+lane],     g1 = sG[w*256+64+lane];
      const float g2 = sG[w*256+128+lane], g3 = sG[w*256+192+lane];
      c_reg = sigf(g1)*c_reg + sigf(g0)*tanh_fast(g2);
      const float h = sigf(g3)*tanh_fast(c_reg);
      sHb[w*64+lane] = h;
      __builtin_amdgcn_wave_barrier();

      if (it >= 7){
        // mix: m[lane] = Wc[lane,:]·h + mbias
        float m0 = mb, m1 = 0.f, m2 = 0.f, m3 = 0.f;
#pragma unroll
        for (int q=0;q<16;q+=4){
          m0 += dot4(sWc[q*64+lane],     sH4w[q]);
          m1 += dot4(sWc[(q+1)*64+lane], sH4w[q+1]);
          m2 += dot4(sWc[(q+2)*64+lane], sH4w[q+2]);
          m3 += dot4(sWc[(q+3)*64+lane], sH4w[q+3]);
        }
        sM[w*64+lane] = (m0+m1)+(m2+m3);
        __builtin_amdgcn_wave_barrier();

        // MLP1 (32x64): row rr, k-half hf
        float u = 0.f;
#pragma unroll
        for (int q=0;q<8;++q) u += dot4(sW1[(hf*8+q)*32+rr], sM4w[hf*8+q]);
        u += __shfl_xor(u, 32);
        if (lane < 32) sA1[w*32+lane] = lrelu(u + b1r);
        __builtin_amdgcn_wave_barrier();

        // MLP2 (32x32): row rr, k-half hf
        float v = 0.f;
#pragma unroll
        for (int q=0;q<4;++q) v += dot4(sW2[(hf*4+q)*32+rr], sA14w[hf*4+q]);
        v += __shfl_xor(v, 32);
        const float a2v = lrelu(v + b2r);

        // head (2x32): butterfly; result replicated in all lanes
        float q0 = a2v*w30, q1 = a2v*w31;
#pragma unroll
        for (int m=1;m<=16;m<<=1){
          q0 += __shfl_xor(q0, m);
          q1 += __shfl_xor(q1, m);
        }
        const float y0 = q0 + b30 + bl20 + (bl20 - bl00)*0.5f;
        const float y1 = q1 + b31 + bl21 + (bl21 - bl01)*0.5f;
        bl00 = bl10; bl01 = bl11;
        bl10 = bl20; bl11 = bl21;
        bl20 = y0;   bl21 = y1;
        if (lane == 0){
          sY[w*2+0] = y0; sY[w*2+1] = y1;
          *reinterpret_cast<float2*>(out + (size_t)((blk*4+w)*TS + (it-7))*2)
              = make_float2(y0, y1);
        }
      }
    }
    __syncthreads();   // B2: sHb/sY ready for next gates
  }
}

extern "C" void kernel_launch(void* const* d_in, const int* in_sizes, int n_in,
                              void* d_out, int out_size, void* d_ws, size_t ws_size,
                              hipStream_t stream)
{
  const float* obsv  = (const float*)d_in[0];
  // d_in[1] = teom : never used (teom-LSTM input is zeros)
  const float* Wih_o = (const float*)d_in[2];
  const float* Whh_o = (const float*)d_in[3];
  const float* bih_o = (const float*)d_in[4];
  const float* bhh_o = (const float*)d_in[5];
  // d_in[6] = Wih_t : multiplies zeros, unused
  const float* Whh_t = (const float*)d_in[7];
  const float* bih_t = (const float*)d_in[8];
  const float* bhh_t = (const float*)d_in[9];
  const float* Wof   = (const float*)d_in[10];
  const float* bof   = (const float*)d_in[11];
  const float* Wtf   = (const float*)d_in[12];
  const float* btf   = (const float*)d_in[13];
  const float* Wmix  = (const float*)d_in[14];
  const float* bmix  = (const float*)d_in[15];
  const float* W1    = (const float*)d_in[16];
  const float* b1    = (const float*)d_in[17];
  const float* W2    = (const float*)d_in[18];
  const float* b2    = (const float*)d_in[19];
  const float* W3    = (const float*)d_in[20];
  const float* b3    = (const float*)d_in[21];

  float* wsf = (float*)d_ws;   // [0,4096): Wcomb   [4096,8192): mbias

  precompute_kernel<<<1,256,0,stream>>>(Whh_t,bih_t,bhh_t,Wof,bof,Wtf,btf,
                                        Wmix,bmix, wsf, wsf+4096);
  main_kernel<<<BS/4,256,0,stream>>>(obsv,Wih_o,Whh_o,bih_o,bhh_o,
                                     W1,b1,W2,b2,W3,b3,
                                     wsf, wsf+4096,
                                     (float*)d_out);
}

// Round 4
// 614.258 us; speedup vs baseline: 1.1105x; 1.1105x over previous
//
#include <hip/hip_runtime.h>

#define BS 1024
#define TS 64

__device__ __forceinline__ float sigf(float x){ return 1.f/(1.f+__expf(-x)); }
__device__ __forceinline__ float tanh_fast(float x){
  float cx = fminf(fmaxf(x,-15.f),15.f);
  float e = __expf(2.f*cx);
  return (e-1.f)/(e+1.f);
}
__device__ __forceinline__ float lrelu(float v){ return v>=0.f ? v : 0.1f*v; }
__device__ __forceinline__ float dot4(float4 a, float4 b){
  return a.x*b.x + a.y*b.y + a.z*b.z + a.w*b.w;
}

// ---------------- Kernel A: batch-independent precompute ----------------
// ws_wcomb[64*64] = Wmix[:,64:] @ Wof
// ws_mbias[TS*64] : per-step mix bias (teom LSTM + Wtf + Wmix1 folded)
__global__ __launch_bounds__(256) void precompute_kernel(
    const float* __restrict__ Whh_t, const float* __restrict__ bih_t,
    const float* __restrict__ bhh_t,
    const float* __restrict__ Wof,  const float* __restrict__ bof,
    const float* __restrict__ Wtf,  const float* __restrict__ btf,
    const float* __restrict__ Wmix, const float* __restrict__ bmix,
    float* __restrict__ ws_wcomb, float* __restrict__ ws_mbias)
{
  __shared__ __align__(16) float sHall[TS*64];
  __shared__ __align__(16) float sTs[TS*64];
  __shared__ float sWof[64*64];
  __shared__ float sG[256];
  __shared__ float sBof[64];
  __shared__ float sCmr[64];

  const int t = threadIdx.x;

  float4 wrow[16];
#pragma unroll
  for (int j=0;j<16;++j) wrow[j] = reinterpret_cast<const float4*>(Whh_t + t*64)[j];
  const float btr = bih_t[t] + bhh_t[t];

  for (int i=t;i<4096;i+=256) sWof[i] = Wof[i];
  if (t<64) sBof[t] = bof[t];
  __syncthreads();

  float c_reg = 0.f;
  for (int s=0;s<TS;++s){
    float a0=btr, a1=0.f, a2=0.f, a3=0.f;
    if (s>0){
      const float4* h4 = reinterpret_cast<const float4*>(sHall + (s-1)*64);
#pragma unroll
      for (int j=0;j<16;j+=4){
        a0 += dot4(wrow[j],   h4[j]);
        a1 += dot4(wrow[j+1], h4[j+1]);
        a2 += dot4(wrow[j+2], h4[j+2]);
        a3 += dot4(wrow[j+3], h4[j+3]);
      }
    }
    sG[t] = (a0+a1)+(a2+a3);
    __syncthreads();
    if (t<64){
      float gi=sG[t], gf=sG[64+t], gg=sG[128+t], go=sG[192+t];
      c_reg = sigf(gf)*c_reg + sigf(gi)*tanh_fast(gg);
      sHall[s*64+t] = sigf(go)*tanh_fast(c_reg);
    }
    __syncthreads();
  }

  if (t<64){
    float acc = bmix[t];
    for (int k=0;k<64;++k) acc += Wmix[t*128+64+k]*sBof[k];
    sCmr[t] = acc;
  }
  for (int o=t;o<TS*64;o+=256){
    int s=o>>6, i=o&63;
    float acc = btf[i];
    for (int k=0;k<64;++k) acc += Wtf[i*64+k]*sHall[s*64+k];
    sTs[o] = acc;
  }
  for (int o=t;o<4096;o+=256){
    int r=o>>6, j=o&63;
    float acc = 0.f;
    for (int k=0;k<64;++k) acc += Wmix[r*128+64+k]*sWof[k*64+j];
    ws_wcomb[o] = acc;
  }
  __syncthreads();
  for (int o=t;o<TS*64;o+=256){
    int s=o>>6, j=o&63;
    float acc = sCmr[j];
    for (int k=0;k<64;++k) acc += Wmix[j*128+k]*sTs[s*64+k];
    ws_mbias[o] = acc;
  }
}

// ---------------- Kernel B: 1 batch/block, grid 1024, 4 blocks/CU ----------------
// R1-proven layout, single batch: thread t holds gate row t in 64 VGPR, h via
// broadcast LDS reads. Tail (cell->mix->MLP->head) on ONE wave, rotated per
// block so co-resident blocks' tail chains land on different SIMDs. The 4
// independent block contexts per SIMD hide each other's serial-tail latency
// (the mechanism R1 had 2-deep and R3 lost entirely).
__global__ __launch_bounds__(256, 4) void main_kernel(
    const float* __restrict__ obsv,
    const float* __restrict__ Wih_o, const float* __restrict__ Whh_o,
    const float* __restrict__ bih_o, const float* __restrict__ bhh_o,
    const float* __restrict__ W1, const float* __restrict__ b1,
    const float* __restrict__ W2, const float* __restrict__ b2,
    const float* __restrict__ W3, const float* __restrict__ b3,
    const float* __restrict__ wcomb, const float* __restrict__ mbias,
    float* __restrict__ out)
{
  __shared__ __align__(16) float4 sWc[16*64];  // [q][row] 16 KB
  __shared__ __align__(16) float4 sW1[16*32];  // [q][row] 8 KB
  __shared__ __align__(16) float4 sW2[8*32];   // [q][row] 4 KB
  __shared__ float sG[256];                    // 1 KB
  __shared__ __align__(16) float sHb[64];
  __shared__ __align__(16) float sM[64];
  __shared__ __align__(16) float sA1[32];
  __shared__ float sY[2];
  __shared__ float sObs[16];

  const int t    = threadIdx.x;
  const int blk  = blockIdx.x;
  const int lane = t & 63;
  const int w    = t >> 6;
  const int tw   = (blk + (blk >> 8)) & 3;   // rotated tail wave
  const bool tailw = (w == tw);

  if (t < 64) out[BS*TS*2 + blk*64 + t] = 0.f;   // c_out zeros (1024*64)

  // staging (row->[q][row] transposed-packed)
  for (int i=t;i<1024;i+=256) sWc[i] = reinterpret_cast<const float4*>(wcomb)[(i&63)*16 + (i>>6)];
  for (int i=t;i<512;i+=256)  sW1[i] = reinterpret_cast<const float4*>(W1)[(i&31)*16 + (i>>5)];
  if (t<256)                  sW2[t] = reinterpret_cast<const float4*>(W2)[(t&31)*8 + (t>>5)];
  if (t<16) sObs[t] = obsv[blk*16 + t];
  if (t<64) sHb[t] = 0.f;

  // gate row t weights
  float4 wrow[16];
#pragma unroll
  for (int j=0;j<16;++j) wrow[j] = reinterpret_cast<const float4*>(Whh_o + t*64)[j];
  const float wi0  = Wih_o[2*t];
  const float wi1  = Wih_o[2*t+1];
  const float b_or = bih_o[t] + bhh_o[t];

  // tail-wave constants
  const int rr = lane & 31, hf = lane >> 5;
  const float b1r = b1[rr], b2r = b2[rr];
  const float w30 = W3[rr], w31 = W3[32+rr];
  const float b30 = b3[0],  b31 = b3[1];
  float bl00=0,bl01=0,bl10=0,bl11=0,bl20=0,bl21=0;
  float c_reg = 0.f;

  __syncthreads();   // staging + sHb zero visible

  if (tailw){
    bl00 = sObs[10]; bl01 = sObs[11];
    bl10 = sObs[12]; bl11 = sObs[13];
    bl20 = sObs[14]; bl21 = sObs[15];
  }

  const float4* sH4   = reinterpret_cast<const float4*>(sHb);
  const float4* sM4   = reinterpret_cast<const float4*>(sM);
  const float4* sA14  = reinterpret_cast<const float4*>(sA1);

  for (int it=0; it<71; ++it){
    // prefetch mbias (L2-resident) under gate FMAs
    float mb = 0.f;
    if (tailw && it >= 7) mb = mbias[(it-7)*64 + lane];

    // ---- gates: row t, 1 batch (identical even/odd 2-acc FP order) ----
    float x0, x1;
    if (it < 8){ x0 = sObs[2*it]; x1 = sObs[2*it+1]; }
    else       { x0 = sY[0];      x1 = sY[1]; }
    float a0 = b_or + wi0*x0 + wi1*x1, p0 = 0.f;
#pragma unroll
    for (int q=0;q<16;q+=2){
      a0 += dot4(wrow[q],   sH4[q]);
      p0 += dot4(wrow[q+1], sH4[q+1]);
    }
    sG[t] = a0 + p0;
    __syncthreads();   // B1: sG ready

    // ---- tail (rotated wave) ----
    if (tailw){
      __builtin_amdgcn_s_setprio(1);
      const float g0 = sG[lane],     g1 = sG[64+lane];
      const float g2 = sG[128+lane], g3 = sG[192+lane];
      c_reg = sigf(g1)*c_reg + sigf(g0)*tanh_fast(g2);
      const float h = sigf(g3)*tanh_fast(c_reg);
      sHb[lane] = h;
      __builtin_amdgcn_wave_barrier();

      if (it >= 7){
        // mix: m[lane] = Wc[lane,:]·h + mbias
        float m0 = mb, m1 = 0.f, m2 = 0.f, m3 = 0.f;
#pragma unroll
        for (int q=0;q<16;q+=4){
          m0 += dot4(sWc[q*64+lane],     sH4[q]);
          m1 += dot4(sWc[(q+1)*64+lane], sH4[q+1]);
          m2 += dot4(sWc[(q+2)*64+lane], sH4[q+2]);
          m3 += dot4(sWc[(q+3)*64+lane], sH4[q+3]);
        }
        sM[lane] = (m0+m1)+(m2+m3);
        __builtin_amdgcn_wave_barrier();

        // MLP1 (32x64): row rr, k-half hf
        float u = 0.f;
#pragma unroll
        for (int q=0;q<8;++q) u += dot4(sW1[(hf*8+q)*32+rr], sM4[hf*8+q]);
        u += __shfl_xor(u, 32);
        if (lane < 32) sA1[lane] = lrelu(u + b1r);
        __builtin_amdgcn_wave_barrier();

        // MLP2 (32x32): row rr, k-half hf
        float v = 0.f;
#pragma unroll
        for (int q=0;q<4;++q) v += dot4(sW2[(hf*4+q)*32+rr], sA14[hf*4+q]);
        v += __shfl_xor(v, 32);
        const float a2v = lrelu(v + b2r);

        // head (2x32): butterfly over 32-lane halves
        float q0 = a2v*w30, q1 = a2v*w31;
#pragma unroll
        for (int m=1;m<=16;m<<=1){
          q0 += __shfl_xor(q0, m);
          q1 += __shfl_xor(q1, m);
        }
        const float y0 = q0 + b30 + bl20 + (bl20 - bl00)*0.5f;
        const float y1 = q1 + b31 + bl21 + (bl21 - bl01)*0.5f;
        bl00 = bl10; bl01 = bl11;
        bl10 = bl20; bl11 = bl21;
        bl20 = y0;   bl21 = y1;
        if (lane == 0){
          sY[0] = y0; sY[1] = y1;
          *reinterpret_cast<float2*>(out + (size_t)(blk*TS + (it-7))*2)
              = make_float2(y0, y1);
        }
      }
      __builtin_amdgcn_s_setprio(0);
    }
    __syncthreads();   // B2: sHb/sY ready for next gates
  }
}

extern "C" void kernel_launch(void* const* d_in, const int* in_sizes, int n_in,
                              void* d_out, int out_size, void* d_ws, size_t ws_size,
                              hipStream_t stream)
{
  const float* obsv  = (const float*)d_in[0];
  // d_in[1] = teom : never used (teom-LSTM input is zeros)
  const float* Wih_o = (const float*)d_in[2];
  const float* Whh_o = (const float*)d_in[3];
  const float* bih_o = (const float*)d_in[4];
  const float* bhh_o = (const float*)d_in[5];
  // d_in[6] = Wih_t : multiplies zeros, unused
  const float* Whh_t = (const float*)d_in[7];
  const float* bih_t = (const float*)d_in[8];
  const float* bhh_t = (const float*)d_in[9];
  const float* Wof   = (const float*)d_in[10];
  const float* bof   = (const float*)d_in[11];
  const float* Wtf   = (const float*)d_in[12];
  const float* btf   = (const float*)d_in[13];
  const float* Wmix  = (const float*)d_in[14];
  const float* bmix  = (const float*)d_in[15];
  const float* W1    = (const float*)d_in[16];
  const float* b1    = (const float*)d_in[17];
  const float* W2    = (const float*)d_in[18];
  const float* b2    = (const float*)d_in[19];
  const float* W3    = (const float*)d_in[20];
  const float* b3    = (const float*)d_in[21];

  float* wsf = (float*)d_ws;   // [0,4096): Wcomb   [4096,8192): mbias

  precompute_kernel<<<1,256,0,stream>>>(Whh_t,bih_t,bhh_t,Wof,bof,Wtf,btf,
                                        Wmix,bmix, wsf, wsf+4096);
  main_kernel<<<BS,256,0,stream>>>(obsv,Wih_o,Whh_o,bih_o,bhh_o,
                                   W1,b1,W2,b2,W3,b3,
                                   wsf, wsf+4096,
                                   (float*)d_out);
}

// Round 5
// 536.100 us; speedup vs baseline: 1.2723x; 1.1458x over previous
//
#include <hip/hip_runtime.h>

#define BS 1024
#define TS 64

__device__ __forceinline__ float sigf(float x){ return 1.f/(1.f+__expf(-x)); }
__device__ __forceinline__ float tanh_fast(float x){
  float cx = fminf(fmaxf(x,-15.f),15.f);
  float e = __expf(2.f*cx);
  return (e-1.f)/(e+1.f);
}
__device__ __forceinline__ float lrelu(float v){ return v>=0.f ? v : 0.1f*v; }
__device__ __forceinline__ float dot4(float4 a, float4 b){
  return a.x*b.x + a.y*b.y + a.z*b.z + a.w*b.w;
}

// ---------------- Kernel A: batch-independent precompute ----------------
// ws_wx [32*64]: W1 @ (Wmix[:,64:] @ Wof)   (mix folded into MLP1 — exact)
// ws_mb1[TS*32]: per-step folded bias  W1·(mbias_t) + b1
__global__ __launch_bounds__(256) void precompute_kernel(
    const float* __restrict__ Whh_t, const float* __restrict__ bih_t,
    const float* __restrict__ bhh_t,
    const float* __restrict__ Wof,  const float* __restrict__ bof,
    const float* __restrict__ Wtf,  const float* __restrict__ btf,
    const float* __restrict__ Wmix, const float* __restrict__ bmix,
    const float* __restrict__ W1,   const float* __restrict__ b1,
    float* __restrict__ ws_wx, float* __restrict__ ws_mb1)
{
  __shared__ __align__(16) float sHall[TS*64];
  __shared__ __align__(16) float sTs[TS*64];
  __shared__ float sWof[64*64];
  __shared__ float sWcb[64*64];   // wcomb = Wmix[:,64:] @ Wof
  __shared__ float sMb[TS*64];    // mbias per step
  __shared__ float sG[256];
  __shared__ float sBof[64];
  __shared__ float sCmr[64];

  const int t = threadIdx.x;

  float4 wrow[16];
#pragma unroll
  for (int j=0;j<16;++j) wrow[j] = reinterpret_cast<const float4*>(Whh_t + t*64)[j];
  const float btr = bih_t[t] + bhh_t[t];

  for (int i=t;i<4096;i+=256) sWof[i] = Wof[i];
  if (t<64) sBof[t] = bof[t];
  __syncthreads();

  float c_reg = 0.f;
  for (int s=0;s<TS;++s){
    float a0=btr, a1=0.f, a2=0.f, a3=0.f;
    if (s>0){
      const float4* h4 = reinterpret_cast<const float4*>(sHall + (s-1)*64);
#pragma unroll
      for (int j=0;j<16;j+=4){
        a0 += dot4(wrow[j],   h4[j]);
        a1 += dot4(wrow[j+1], h4[j+1]);
        a2 += dot4(wrow[j+2], h4[j+2]);
        a3 += dot4(wrow[j+3], h4[j+3]);
      }
    }
    sG[t] = (a0+a1)+(a2+a3);
    __syncthreads();
    if (t<64){
      float gi=sG[t], gf=sG[64+t], gg=sG[128+t], go=sG[192+t];
      c_reg = sigf(gf)*c_reg + sigf(gi)*tanh_fast(gg);
      sHall[s*64+t] = sigf(go)*tanh_fast(c_reg);
    }
    __syncthreads();
  }

  if (t<64){
    float acc = bmix[t];
    for (int k=0;k<64;++k) acc += Wmix[t*128+64+k]*sBof[k];
    sCmr[t] = acc;
  }
  for (int o=t;o<TS*64;o+=256){
    int s=o>>6, i=o&63;
    float acc = btf[i];
    for (int k=0;k<64;++k) acc += Wtf[i*64+k]*sHall[s*64+k];
    sTs[o] = acc;
  }
  for (int o=t;o<4096;o+=256){
    int r=o>>6, j=o&63;
    float acc = 0.f;
    for (int k=0;k<64;++k) acc += Wmix[r*128+64+k]*sWof[k*64+j];
    sWcb[o] = acc;
  }
  __syncthreads();
  for (int o=t;o<TS*64;o+=256){
    int s=o>>6, j=o&63;
    float acc = sCmr[j];
    for (int k=0;k<64;++k) acc += Wmix[j*128+k]*sTs[s*64+k];
    sMb[o] = acc;
  }
  __syncthreads();
  // folded outputs
  for (int o=t;o<32*64;o+=256){        // ws_wx[r][j] = sum_k W1[r][k]*wcomb[k][j]
    int r=o>>6, j=o&63;
    float acc = 0.f;
    for (int k=0;k<64;++k) acc += W1[r*64+k]*sWcb[k*64+j];
    ws_wx[o] = acc;
  }
  for (int o=t;o<TS*32;o+=256){        // ws_mb1[s][r] = b1[r] + sum_k W1[r][k]*mbias[s][k]
    int s=o>>5, r=o&31;
    float acc = b1[r];
    for (int k=0;k<64;++k) acc += W1[r*64+k]*sMb[s*64+k];
    ws_mb1[o] = acc;
  }
}

// ---------------- Kernel B: 128 thr, 2 waves, 1 barrier/step, redundant tail ----------------
// Thread (w,lane) holds gate rows w*128+lane and w*128+64+lane in 128 VGPR.
// Per step: gates -> sG (double-buffered) -> ONE __syncthreads -> both waves
// redundantly: cell (h into wave-private sHb copy) -> folded MLP1 (Wx=W1@Wc)
// -> MLP2 -> head butterfly -> y kept IN-REGISTER (no sY, no 2nd barrier).
__global__ __launch_bounds__(128, 2) void main_kernel(
    const float* __restrict__ obsv,
    const float* __restrict__ Wih_o, const float* __restrict__ Whh_o,
    const float* __restrict__ bih_o, const float* __restrict__ bhh_o,
    const float* __restrict__ W2, const float* __restrict__ b2,
    const float* __restrict__ W3, const float* __restrict__ b3,
    const float* __restrict__ wx, const float* __restrict__ mb1,
    float* __restrict__ out)
{
  __shared__ __align__(16) float4 sWx[16*32];  // [q][row] 8 KB  (folded W1@Wc)
  __shared__ __align__(16) float4 sW2[8*32];   // [q][row] 4 KB
  __shared__ float sG[2][256];                 // double-buffered gate exchange
  __shared__ __align__(16) float sHb[2][64];   // wave-private h copies
  __shared__ __align__(16) float sA1[2][32];   // wave-private a1 copies
  __shared__ float sObs[16];

  const int t    = threadIdx.x;
  const int blk  = blockIdx.x;     // = batch
  const int lane = t & 63;
  const int w    = t >> 6;         // 0 or 1

  if (t < 64) out[BS*TS*2 + blk*64 + t] = 0.f;   // c_out zeros (1024*64)

  // staging (row->[q][row] transposed-packed)
  for (int i=t;i<512;i+=128) sWx[i] = reinterpret_cast<const float4*>(wx)[(i&31)*16 + (i>>5)];
  for (int i=t;i<256;i+=128) sW2[i] = reinterpret_cast<const float4*>(W2)[(i&31)*8 + (i>>5)];
  if (t<16) sObs[t] = obsv[blk*16 + t];
  sHb[t>>6][t&63] = 0.f;           // zero both copies

  // gate rows r0 = w*128+lane, r1 = w*128+64+lane (32 float4 = 128 VGPR)
  const int r0 = w*128 + lane, r1 = r0 + 64;
  float4 wr0[16], wr1[16];
#pragma unroll
  for (int j=0;j<16;++j){
    wr0[j] = reinterpret_cast<const float4*>(Whh_o + r0*64)[j];
    wr1[j] = reinterpret_cast<const float4*>(Whh_o + r1*64)[j];
  }
  const float wi00 = Wih_o[2*r0], wi01 = Wih_o[2*r0+1];
  const float wi10 = Wih_o[2*r1], wi11 = Wih_o[2*r1+1];
  const float bR0 = bih_o[r0] + bhh_o[r0];
  const float bR1 = bih_o[r1] + bhh_o[r1];

  // tail constants (both waves run the tail redundantly)
  const int rr = lane & 31, hf = lane >> 5;
  const float b2r = b2[rr];
  const float w30 = W3[rr], w31 = W3[32+rr];
  const float b30 = b3[0],  b31 = b3[1];

  __syncthreads();   // staging + sHb zero visible

  float bl00 = sObs[10], bl01 = sObs[11];
  float bl10 = sObs[12], bl11 = sObs[13];
  float bl20 = sObs[14], bl21 = sObs[15];
  float c_reg = 0.f, y0r = 0.f, y1r = 0.f;

  const float4* sH4w  = reinterpret_cast<const float4*>(sHb[w]);
  const float4* sA14w = reinterpret_cast<const float4*>(sA1[w]);

  for (int it=0; it<71; ++it){
    // prefetch folded bias (L2-resident) under gate FMAs
    float mb = 0.f;
    if (it >= 7) mb = mb1[(it-7)*32 + rr];

    // ---- gates: 2 rows/lane, identical even/odd 2-acc FP order per row ----
    float x0, x1;
    if (it < 8){ x0 = sObs[2*it]; x1 = sObs[2*it+1]; }
    else       { x0 = y0r;        x1 = y1r; }
    float a0 = bR0 + wi00*x0 + wi01*x1, p0 = 0.f;
    float a1 = bR1 + wi10*x0 + wi11*x1, p1 = 0.f;
#pragma unroll
    for (int q=0;q<16;q+=2){
      const float4 h0 = sH4w[q], h1 = sH4w[q+1];
      a0 += dot4(wr0[q],h0);  p0 += dot4(wr0[q+1],h1);
      a1 += dot4(wr1[q],h0);  p1 += dot4(wr1[q+1],h1);
    }
    const int pb = it & 1;
    sG[pb][r0] = a0 + p0;
    sG[pb][r1] = a1 + p1;
    __syncthreads();   // ONLY barrier: sG ready (write->read; reverse dir covered by dbuf)

    // ---- cell + tail, redundant in BOTH waves (wave-private buffers) ----
    const float g0 = sG[pb][lane],     g1 = sG[pb][64+lane];
    const float g2 = sG[pb][128+lane], g3 = sG[pb][192+lane];
    c_reg = sigf(g1)*c_reg + sigf(g0)*tanh_fast(g2);
    const float h = sigf(g3)*tanh_fast(c_reg);
    sHb[w][lane] = h;
    __builtin_amdgcn_wave_barrier();

    if (it >= 7){
      // folded MLP1 (32x64): row rr, k-half hf; bias mb already includes W1·mbias + b1
      float u = 0.f;
#pragma unroll
      for (int q=0;q<8;++q) u += dot4(sWx[(hf*8+q)*32+rr], sH4w[hf*8+q]);
      u += __shfl_xor(u, 32);
      if (lane < 32) sA1[w][lane] = lrelu(u + mb);
      __builtin_amdgcn_wave_barrier();

      // MLP2 (32x32): row rr, k-half hf
      float v = 0.f;
#pragma unroll
      for (int q=0;q<4;++q) v += dot4(sW2[(hf*4+q)*32+rr], sA14w[hf*4+q]);
      v += __shfl_xor(v, 32);
      const float a2v = lrelu(v + b2r);

      // head (2x32): butterfly; y replicated in all lanes of both waves
      float q0 = a2v*w30, q1 = a2v*w31;
#pragma unroll
      for (int m=1;m<=16;m<<=1){
        q0 += __shfl_xor(q0, m);
        q1 += __shfl_xor(q1, m);
      }
      const float y0 = q0 + b30 + bl20 + (bl20 - bl00)*0.5f;
      const float y1 = q1 + b31 + bl21 + (bl21 - bl01)*0.5f;
      bl00 = bl10; bl01 = bl11;
      bl10 = bl20; bl11 = bl21;
      bl20 = y0;   bl21 = y1;
      y0r = y0;    y1r = y1;        // feedback in-register (no sY, no barrier)
      if (w == 0 && lane == 0)
        *reinterpret_cast<float2*>(out + (size_t)(blk*TS + (it-7))*2)
            = make_float2(y0, y1);
    }
  }
}

extern "C" void kernel_launch(void* const* d_in, const int* in_sizes, int n_in,
                              void* d_out, int out_size, void* d_ws, size_t ws_size,
                              hipStream_t stream)
{
  const float* obsv  = (const float*)d_in[0];
  // d_in[1] = teom : never used (teom-LSTM input is zeros)
  const float* Wih_o = (const float*)d_in[2];
  const float* Whh_o = (const float*)d_in[3];
  const float* bih_o = (const float*)d_in[4];
  const float* bhh_o = (const float*)d_in[5];
  // d_in[6] = Wih_t : multiplies zeros, unused
  const float* Whh_t = (const float*)d_in[7];
  const float* bih_t = (const float*)d_in[8];
  const float* bhh_t = (const float*)d_in[9];
  const float* Wof   = (const float*)d_in[10];
  const float* bof   = (const float*)d_in[11];
  const float* Wtf   = (const float*)d_in[12];
  const float* btf   = (const float*)d_in[13];
  const float* Wmix  = (const float*)d_in[14];
  const float* bmix  = (const float*)d_in[15];
  const float* W1    = (const float*)d_in[16];
  const float* b1    = (const float*)d_in[17];
  const float* W2    = (const float*)d_in[18];
  const float* b2    = (const float*)d_in[19];
  const float* W3    = (const float*)d_in[20];
  const float* b3    = (const float*)d_in[21];

  float* wsf = (float*)d_ws;   // [0,2048): Wx   [2048,4096+...): mb1

  precompute_kernel<<<1,256,0,stream>>>(Whh_t,bih_t,bhh_t,Wof,bof,Wtf,btf,
                                        Wmix,bmix, W1,b1, wsf, wsf+2048);
  main_kernel<<<BS,128,0,stream>>>(obsv,Wih_o,Whh_o,bih_o,bhh_o,
                                   W2,b2,W3,b3,
                                   wsf, wsf+2048,
                                   (float*)d_out);
}